// Round 7
// baseline (114.383 us; speedup 1.0000x reference)
//
#include <hip/hip_runtime.h>

// RegionalCosineSimilarityLoss — B=8, T=2048, C=128; mapping sorted per batch, [0,64).
// mask(t,s) = (s>t) & (m_s <= m_t+3) & (m_t != 0)   [sortedness folds neighbor+padding]
// R7: R5 structure, scaffolding hoisted — searches run as extra k_prep blocks
// (parallel, off k_tile's critical path); k_final folded into k_tile via
// deterministic last-block reduce. Two dispatches total.

#define TT 2048
#define CC 128
#define TM 64
#define SLOTS 4
#define NTILES 256
#define TOTAL_BLK (NTILES * SLOTS)   // 1024
#define NORM_BLKS 4096               // 16384 rows / 4 rows-per-block
#define SEARCH_BLKS 64               // 16384 rows / 256 searches-per-block

typedef unsigned short ushort_t;
typedef __attribute__((ext_vector_type(8))) short v8s;   // 8 bf16 (4 VGPRs)
typedef __attribute__((ext_vector_type(4))) float v4f;   // MFMA accumulator

__device__ __forceinline__ ushort_t f2bf(float f) {      // RNE f32->bf16 (finite data)
    unsigned u = __float_as_uint(f);
    return (ushort_t)((u + 0x7FFFu + ((u >> 16) & 1u)) >> 16);
}

// ---------------- Kernel 1: normalize->bf16  +  parallel band searches ----------------
// Blocks [0,4096): wave-per-row normalize (R5-validated). Blocks [4096,4160):
// one binary search per thread; wave = one 64-row tile -> emax/pcnt via shfl.
__global__ void __launch_bounds__(256) k_prep(const float* __restrict__ x,
                                              const int* __restrict__ map,
                                              ushort_t* __restrict__ xnb,
                                              int* __restrict__ et,
                                              int* __restrict__ emax_g,
                                              int* __restrict__ pcnt,
                                              unsigned* __restrict__ done) {
    const int bid = blockIdx.x;
    const int tid = threadIdx.x;
    if (bid == 0 && tid == 0) *done = 0u;     // reset completion counter every call

    if (bid < NORM_BLKS) {
        const int wave = tid >> 6, lane = tid & 63;
        const int row  = bid * 4 + wave;
        float2 v = ((const float2*)(x + (size_t)row * CC))[lane];
        float ss = v.x * v.x + v.y * v.y;
        #pragma unroll
        for (int off = 32; off; off >>= 1) ss += __shfl_xor(ss, off);
        const float rn = 1.0f / fmaxf(sqrtf(ss), 1e-8f);
        const unsigned lo = f2bf(v.x * rn), hi = f2bf(v.y * rn);
        ((unsigned*)(xnb + (size_t)row * CC))[lane] = lo | (hi << 16);
    } else {
        const int row = (bid - NORM_BLKS) * 256 + tid;    // global row = tile*64 + i
        const int t   = row & (TT - 1);
        const int* mb = map + (row >> 11) * TT;
        const int m   = mb[t];
        int e = t;                                        // empty band when m==0
        if (m != 0) {
            const int key = m + 3;
            int lo = t + 1, hi = TT;
            while (lo < hi) { int mid = (lo + hi) >> 1; if (mb[mid] <= key) lo = mid + 1; else hi = mid; }
            e = lo - 1;
        }
        et[row] = e;
        int c = e - t, mx = e;
        #pragma unroll
        for (int off = 32; off; off >>= 1) {
            c  += __shfl_xor(c, off);
            mx  = max(mx, __shfl_xor(mx, off));
        }
        if ((tid & 63) == 0) {
            const int tile = row >> 6;
            pcnt[tile] = c; emax_g[tile] = mx;
        }
    }
}

// ---------------- Kernel 2: MFMA band tiles + last-block final reduce ----------------
// 4 waves; wave (wr,wc) owns a 32x32 quadrant of the 64x64 tile.
// LDS bf16 [64 rows][16 chunks of 16B], chunk-slot swizzle sl^=(row&7),
// linear LDS dst + pre-swizzled global src (global_load_lds).  [R5-validated core]
__global__ void __launch_bounds__(256) k_tile(const ushort_t* __restrict__ xnb,
                                              const int* __restrict__ map,
                                              const int* __restrict__ et,
                                              const int* __restrict__ emax_g,
                                              const int* __restrict__ pcnt,
                                              float* __restrict__ psum,
                                              unsigned* __restrict__ done,
                                              float* __restrict__ out) {
    __shared__ __align__(16) ushort_t As[TM * CC];   // 16 KB
    __shared__ __align__(16) ushort_t Bs[TM * CC];   // 16 KB
    __shared__ int mt_s[TM], et_s[TM], ms_s[TM];
    __shared__ float wsum[4];
    __shared__ unsigned s_old;

    const int tile = blockIdx.x;              // 0..255
    const int slot = blockIdx.y;              // 0..SLOTS-1
    const int tid  = threadIdx.x;
    const int lane = tid & 63;
    const int wave = tid >> 6;
    const int b    = tile >> 5;
    const int t0   = (tile & 31) * TM;
    const int* mb  = map + b * TT;
    const ushort_t* xb = xnb + (size_t)(b * TT) * CC;

    const int emax = emax_g[tile];
    int s_base = t0 + slot * TM;
    float blocksum = 0.0f;

    if (s_base <= emax) {                     // active slot (branch is block-uniform)
        // ---- stage A: linear LDS dst, pre-swizzled global src ----
        #pragma unroll
        for (int i = 0; i < 4; ++i) {
            const int pbase = wave * 256 + i * 64;
            const int p = pbase + lane;
            const int row = p >> 4;
            const int sl  = (p & 15) ^ (row & 7);
            __builtin_amdgcn_global_load_lds(
                (const __attribute__((address_space(1))) void*)(xb + (size_t)(t0 + row) * CC + sl * 8),
                (__attribute__((address_space(3))) void*)(&As[pbase * 8]), 16, 0, 0);
        }
        if (tid < TM) {
            mt_s[tid] = mb[t0 + tid];
            et_s[tid] = et[b * TT + t0 + tid];
        }

        const int wr = wave >> 1, wc = wave & 1;
        const int r16 = lane & 15, kgrp = lane >> 4;
        const int rowA0 = wr * 32 + r16, rowA1 = rowA0 + 16;
        const int rowB0 = wc * 32 + r16, rowB1 = rowB0 + 16;

        float lsum = 0.0f;

        for (; s_base <= emax; s_base += SLOTS * TM) {
            // ---- stage B chunk + its map values ----
            #pragma unroll
            for (int i = 0; i < 4; ++i) {
                const int pbase = wave * 256 + i * 64;
                const int p = pbase + lane;
                const int row = p >> 4;
                const int sl  = (p & 15) ^ (row & 7);
                __builtin_amdgcn_global_load_lds(
                    (const __attribute__((address_space(1))) void*)(xb + (size_t)(s_base + row) * CC + sl * 8),
                    (__attribute__((address_space(3))) void*)(&Bs[pbase * 8]), 16, 0, 0);
            }
            if (tid < TM) ms_s[tid] = mb[s_base + tid];
            __syncthreads();   // drains global_load_lds + publishes mt_s/et_s/ms_s

            v4f acc00 = {0,0,0,0}, acc01 = {0,0,0,0}, acc10 = {0,0,0,0}, acc11 = {0,0,0,0};
            #pragma unroll
            for (int kk = 0; kk < 4; ++kk) {
                const int sl = kk * 4 + kgrp;
                v8s a0 = *(const v8s*)&As[(rowA0 * 16 + (sl ^ (rowA0 & 7))) * 8];
                v8s a1 = *(const v8s*)&As[(rowA1 * 16 + (sl ^ (rowA1 & 7))) * 8];
                v8s b0 = *(const v8s*)&Bs[(rowB0 * 16 + (sl ^ (rowB0 & 7))) * 8];
                v8s b1 = *(const v8s*)&Bs[(rowB1 * 16 + (sl ^ (rowB1 & 7))) * 8];
                acc00 = __builtin_amdgcn_mfma_f32_16x16x32_bf16(a0, b0, acc00, 0, 0, 0);
                acc01 = __builtin_amdgcn_mfma_f32_16x16x32_bf16(a0, b1, acc01, 0, 0, 0);
                acc10 = __builtin_amdgcn_mfma_f32_16x16x32_bf16(a1, b0, acc10, 0, 0, 0);
                acc11 = __builtin_amdgcn_mfma_f32_16x16x32_bf16(a1, b1, acc11, 0, 0, 0);
            }

            // ---- masked epilogue: C row=(lane>>4)*4+reg (t), col=lane&15 (s) ----
            #pragma unroll
            for (int fi = 0; fi < 2; ++fi) {
                #pragma unroll
                for (int fj = 0; fj < 2; ++fj) {
                    const v4f a = fi == 0 ? (fj == 0 ? acc00 : acc01) : (fj == 0 ? acc10 : acc11);
                    const int s_loc = wc * 32 + fj * 16 + r16;
                    const int s     = s_base + s_loc;
                    const int m_s   = ms_s[s_loc];
                    #pragma unroll
                    for (int r = 0; r < 4; ++r) {
                        const int t_loc = wr * 32 + fi * 16 + kgrp * 4 + r;
                        const int t     = t0 + t_loc;
                        const int m_t   = mt_s[t_loc];
                        if ((m_t != 0) & (s > t) & (s <= et_s[t_loc])) {
                            const float d = a[r] - (m_s == m_t ? 1.0f : 0.0f);
                            lsum += d * d;
                        }
                    }
                }
            }
            __syncthreads();   // protect Bs/ms before restage (rare multi-pass)
        }

        #pragma unroll
        for (int off = 32; off; off >>= 1) lsum += __shfl_xor(lsum, off);
        if (lane == 0) wsum[wave] = lsum;
        __syncthreads();
        if (tid == 0) blocksum = wsum[0] + wsum[1] + wsum[2] + wsum[3];
    }

    // ---- completion: publish partial, last block reduces deterministically ----
    if (tid == 0) psum[tile * SLOTS + slot] = blocksum;
    __threadfence();
    if (tid == 0) s_old = atomicAdd(done, 1u);
    __syncthreads();
    if (s_old == TOTAL_BLK - 1) {
        __threadfence();                       // acquire: all psum writes visible
        __shared__ double ssum[256];
        __shared__ long long scnt[256];
        double s = 0.0; long long c = 0;
        for (int i = tid; i < TOTAL_BLK; i += 256) s += (double)psum[i];
        for (int i = tid; i < NTILES; i += 256) c += (long long)pcnt[i];
        ssum[tid] = s; scnt[tid] = c;
        __syncthreads();
        #pragma unroll
        for (int off = 128; off; off >>= 1) {
            if (tid < off) { ssum[tid] += ssum[tid + off]; scnt[tid] += scnt[tid + off]; }
            __syncthreads();
        }
        if (tid == 0) out[0] = (float)(ssum[0] / ((double)scnt[0] + 1e-6));
    }
}

extern "C" void kernel_launch(void* const* d_in, const int* in_sizes, int n_in,
                              void* d_out, int out_size, void* d_ws, size_t ws_size,
                              hipStream_t stream) {
    (void)n_in; (void)out_size; (void)ws_size;
    const float* x   = (const float*)d_in[0];
    const int*   map = (const int*)d_in[1];
    float* out = (float*)d_out;

    const int n_rows = in_sizes[1];             // B*T = 16384

    ushort_t* xnb  = (ushort_t*)d_ws;                                   // 4 MiB
    char*     p    = (char*)d_ws + (size_t)n_rows * CC * 2;
    int*      etw  = (int*)p;                   p += (size_t)n_rows * 4;      // 64 KiB
    int*      emax = (int*)p;                   p += (size_t)NTILES * 4;
    int*      pc   = (int*)p;                   p += (size_t)NTILES * 4;
    float*    ps   = (float*)p;                 p += (size_t)TOTAL_BLK * 4;
    unsigned* done = (unsigned*)p;

    k_prep<<<NORM_BLKS + SEARCH_BLKS, 256, 0, stream>>>(x, map, xnb, etw, emax, pc, done);
    k_tile<<<dim3(NTILES, SLOTS), 256, 0, stream>>>(xnb, map, etw, emax, pc, ps, done, out);
}

// Round 8
// 20.419 us; speedup vs baseline: 5.6018x; 5.6018x over previous
//
#include <hip/hip_runtime.h>

// RegionalCosineSimilarityLoss — B=8, T=2048, C=128; mapping sorted per batch, [0,64).
// mask(t,s) = (s>t) & (m_s <= m_t+3) & (m_t != 0)   [sortedness folds neighbor+padding]
// R8: R7 minus the last-block atomic reduce (104us same-line fence serialization!).
// k_prep: normalize blocks + parallel search blocks. k_tile: pure MFMA band tiles,
// no atomics. k_final: tiny separate reduce. Three dispatches.

#define TT 2048
#define CC 128
#define TM 64
#define SLOTS 4
#define NTILES 256
#define TOTAL_BLK (NTILES * SLOTS)   // 1024
#define NORM_BLKS 4096               // 16384 rows / 4 rows-per-block
#define SEARCH_BLKS 64               // 16384 rows / 256 searches-per-block

typedef unsigned short ushort_t;
typedef __attribute__((ext_vector_type(8))) short v8s;   // 8 bf16 (4 VGPRs)
typedef __attribute__((ext_vector_type(4))) float v4f;   // MFMA accumulator

__device__ __forceinline__ ushort_t f2bf(float f) {      // RNE f32->bf16 (finite data)
    unsigned u = __float_as_uint(f);
    return (ushort_t)((u + 0x7FFFu + ((u >> 16) & 1u)) >> 16);
}

// ---------------- Kernel 1: normalize->bf16  +  parallel band searches ----------------
__global__ void __launch_bounds__(256) k_prep(const float* __restrict__ x,
                                              const int* __restrict__ map,
                                              ushort_t* __restrict__ xnb,
                                              int* __restrict__ et,
                                              int* __restrict__ emax_g,
                                              int* __restrict__ pcnt) {
    const int bid = blockIdx.x;
    const int tid = threadIdx.x;

    if (bid < NORM_BLKS) {
        const int wave = tid >> 6, lane = tid & 63;
        const int row  = bid * 4 + wave;
        float2 v = ((const float2*)(x + (size_t)row * CC))[lane];
        float ss = v.x * v.x + v.y * v.y;
        #pragma unroll
        for (int off = 32; off; off >>= 1) ss += __shfl_xor(ss, off);
        const float rn = 1.0f / fmaxf(sqrtf(ss), 1e-8f);
        const unsigned lo = f2bf(v.x * rn), hi = f2bf(v.y * rn);
        ((unsigned*)(xnb + (size_t)row * CC))[lane] = lo | (hi << 16);
    } else {
        const int row = (bid - NORM_BLKS) * 256 + tid;    // global row = tile*64 + i
        const int t   = row & (TT - 1);
        const int* mb = map + (row >> 11) * TT;
        const int m   = mb[t];
        int e = t;                                        // empty band when m==0
        if (m != 0) {
            const int key = m + 3;
            int lo = t + 1, hi = TT;
            while (lo < hi) { int mid = (lo + hi) >> 1; if (mb[mid] <= key) lo = mid + 1; else hi = mid; }
            e = lo - 1;
        }
        et[row] = e;
        int c = e - t, mx = e;
        #pragma unroll
        for (int off = 32; off; off >>= 1) {
            c  += __shfl_xor(c, off);
            mx  = max(mx, __shfl_xor(mx, off));
        }
        if ((tid & 63) == 0) {
            const int tile = row >> 6;
            pcnt[tile] = c; emax_g[tile] = mx;
        }
    }
}

// ---------------- Kernel 2: MFMA band tiles (no atomics) ----------------
// 4 waves; wave (wr,wc) owns a 32x32 quadrant of the 64x64 tile.
// LDS bf16 [64 rows][16 chunks of 16B], chunk-slot swizzle sl^=(row&7),
// linear LDS dst + pre-swizzled global src (global_load_lds).  [R5-validated core]
__global__ void __launch_bounds__(256) k_tile(const ushort_t* __restrict__ xnb,
                                              const int* __restrict__ map,
                                              const int* __restrict__ et,
                                              const int* __restrict__ emax_g,
                                              float* __restrict__ psum) {
    __shared__ __align__(16) ushort_t As[TM * CC];   // 16 KB
    __shared__ __align__(16) ushort_t Bs[TM * CC];   // 16 KB
    __shared__ int mt_s[TM], et_s[TM], ms_s[TM];
    __shared__ float wsum[4];

    const int tile = blockIdx.x;              // 0..255
    const int slot = blockIdx.y;              // 0..SLOTS-1
    const int tid  = threadIdx.x;
    const int lane = tid & 63;
    const int wave = tid >> 6;
    const int b    = tile >> 5;
    const int t0   = (tile & 31) * TM;
    const int* mb  = map + b * TT;
    const ushort_t* xb = xnb + (size_t)(b * TT) * CC;

    const int emax = emax_g[tile];
    int s_base = t0 + slot * TM;
    if (s_base > emax) {                      // inactive slot: cheap exit
        if (tid == 0) psum[tile * SLOTS + slot] = 0.0f;
        return;
    }

    // ---- stage A: linear LDS dst, pre-swizzled global src ----
    #pragma unroll
    for (int i = 0; i < 4; ++i) {
        const int pbase = wave * 256 + i * 64;
        const int p = pbase + lane;
        const int row = p >> 4;
        const int sl  = (p & 15) ^ (row & 7);
        __builtin_amdgcn_global_load_lds(
            (const __attribute__((address_space(1))) void*)(xb + (size_t)(t0 + row) * CC + sl * 8),
            (__attribute__((address_space(3))) void*)(&As[pbase * 8]), 16, 0, 0);
    }
    if (tid < TM) {
        mt_s[tid] = mb[t0 + tid];
        et_s[tid] = et[b * TT + t0 + tid];
    }

    const int wr = wave >> 1, wc = wave & 1;
    const int r16 = lane & 15, kgrp = lane >> 4;
    const int rowA0 = wr * 32 + r16, rowA1 = rowA0 + 16;
    const int rowB0 = wc * 32 + r16, rowB1 = rowB0 + 16;

    float lsum = 0.0f;

    for (; s_base <= emax; s_base += SLOTS * TM) {
        // ---- stage B chunk + its map values ----
        #pragma unroll
        for (int i = 0; i < 4; ++i) {
            const int pbase = wave * 256 + i * 64;
            const int p = pbase + lane;
            const int row = p >> 4;
            const int sl  = (p & 15) ^ (row & 7);
            __builtin_amdgcn_global_load_lds(
                (const __attribute__((address_space(1))) void*)(xb + (size_t)(s_base + row) * CC + sl * 8),
                (__attribute__((address_space(3))) void*)(&Bs[pbase * 8]), 16, 0, 0);
        }
        if (tid < TM) ms_s[tid] = mb[s_base + tid];
        __syncthreads();   // drains global_load_lds + publishes mt_s/et_s/ms_s

        v4f acc00 = {0,0,0,0}, acc01 = {0,0,0,0}, acc10 = {0,0,0,0}, acc11 = {0,0,0,0};
        #pragma unroll
        for (int kk = 0; kk < 4; ++kk) {
            const int sl = kk * 4 + kgrp;
            v8s a0 = *(const v8s*)&As[(rowA0 * 16 + (sl ^ (rowA0 & 7))) * 8];
            v8s a1 = *(const v8s*)&As[(rowA1 * 16 + (sl ^ (rowA1 & 7))) * 8];
            v8s b0 = *(const v8s*)&Bs[(rowB0 * 16 + (sl ^ (rowB0 & 7))) * 8];
            v8s b1 = *(const v8s*)&Bs[(rowB1 * 16 + (sl ^ (rowB1 & 7))) * 8];
            acc00 = __builtin_amdgcn_mfma_f32_16x16x32_bf16(a0, b0, acc00, 0, 0, 0);
            acc01 = __builtin_amdgcn_mfma_f32_16x16x32_bf16(a0, b1, acc01, 0, 0, 0);
            acc10 = __builtin_amdgcn_mfma_f32_16x16x32_bf16(a1, b0, acc10, 0, 0, 0);
            acc11 = __builtin_amdgcn_mfma_f32_16x16x32_bf16(a1, b1, acc11, 0, 0, 0);
        }

        // ---- masked epilogue: C row=(lane>>4)*4+reg (t), col=lane&15 (s) ----
        #pragma unroll
        for (int fi = 0; fi < 2; ++fi) {
            #pragma unroll
            for (int fj = 0; fj < 2; ++fj) {
                const v4f a = fi == 0 ? (fj == 0 ? acc00 : acc01) : (fj == 0 ? acc10 : acc11);
                const int s_loc = wc * 32 + fj * 16 + r16;
                const int s     = s_base + s_loc;
                const int m_s   = ms_s[s_loc];
                #pragma unroll
                for (int r = 0; r < 4; ++r) {
                    const int t_loc = wr * 32 + fi * 16 + kgrp * 4 + r;
                    const int t     = t0 + t_loc;
                    const int m_t   = mt_s[t_loc];
                    if ((m_t != 0) & (s > t) & (s <= et_s[t_loc])) {
                        const float d = a[r] - (m_s == m_t ? 1.0f : 0.0f);
                        lsum += d * d;
                    }
                }
            }
        }
        __syncthreads();   // protect Bs/ms before restage (rare multi-pass)
    }

    #pragma unroll
    for (int off = 32; off; off >>= 1) lsum += __shfl_xor(lsum, off);
    if (lane == 0) wsum[wave] = lsum;
    __syncthreads();
    if (tid == 0) psum[tile * SLOTS + slot] = wsum[0] + wsum[1] + wsum[2] + wsum[3];
}

// ---------------- Kernel 3: final reduce (tiny reads) ----------------
__global__ void __launch_bounds__(256) k_final(const float* __restrict__ psum,
                                               const int* __restrict__ pcnt,
                                               float* __restrict__ out,
                                               int n_sum, int n_cnt) {
    __shared__ double ssum[256];
    __shared__ long long scnt[256];
    double s = 0.0; long long c = 0;
    for (int i = threadIdx.x; i < n_sum; i += 256) s += (double)psum[i];
    for (int i = threadIdx.x; i < n_cnt; i += 256) c += (long long)pcnt[i];
    ssum[threadIdx.x] = s; scnt[threadIdx.x] = c;
    __syncthreads();
    #pragma unroll
    for (int off = 128; off; off >>= 1) {
        if (threadIdx.x < off) {
            ssum[threadIdx.x] += ssum[threadIdx.x + off];
            scnt[threadIdx.x] += scnt[threadIdx.x + off];
        }
        __syncthreads();
    }
    if (threadIdx.x == 0) out[0] = (float)(ssum[0] / ((double)scnt[0] + 1e-6));
}

extern "C" void kernel_launch(void* const* d_in, const int* in_sizes, int n_in,
                              void* d_out, int out_size, void* d_ws, size_t ws_size,
                              hipStream_t stream) {
    (void)n_in; (void)out_size; (void)ws_size;
    const float* x   = (const float*)d_in[0];
    const int*   map = (const int*)d_in[1];
    float* out = (float*)d_out;

    const int n_rows = in_sizes[1];             // B*T = 16384

    ushort_t* xnb  = (ushort_t*)d_ws;                                   // 4 MiB
    char*     p    = (char*)d_ws + (size_t)n_rows * CC * 2;
    int*      etw  = (int*)p;                   p += (size_t)n_rows * 4;      // 64 KiB
    int*      emax = (int*)p;                   p += (size_t)NTILES * 4;
    int*      pc   = (int*)p;                   p += (size_t)NTILES * 4;
    float*    ps   = (float*)p;

    k_prep <<<NORM_BLKS + SEARCH_BLKS, 256, 0, stream>>>(x, map, xnb, etw, emax, pc);
    k_tile <<<dim3(NTILES, SLOTS), 256, 0, stream>>>(xnb, map, etw, emax, ps);
    k_final<<<1, 256, 0, stream>>>(ps, pc, out, TOTAL_BLK, NTILES);
}